// Round 17
// baseline (81.975 us; speedup 1.0000x reference)
//
#include <hip/hip_runtime.h>

// FullFreqAttention: B=8, L=S=1024, H=8, E=D=64
// scores = complex QK^T (no conj); A = softmax(0.125*|scores|); out = stack(A@v_re, A@v_im)
//
// Pass 1: prepack K/V -> bf16 FRAGMENT-ORDERED tile images in d_ws.
// Pass 2: flash kernel, 4 waves x 32 q-rows (QB=128, grid 512). Full 32KB tile staged
//   into LDS (global_load_lds w16, double-buffered 64KB). Dual-QK ILP (both halves'
//   QK back-to-back, 4 independent score chains), V frags just-in-time from LDS.
//   THIS ROUND: all s_setprio removed (never A/B'd; T5 hurts lockstep structures per
//   m190) + qimn precomputed (keeps XORs out of the MFMA-feeding path).
//   Compute core: swapped-operand 32x32x16 MFMA, in-register softmax
//   (v_cvt_pk_bf16_f32 + v_permlane32_swap_b32), fixed softmax max = 0.

#define B_ 8
#define L_ 1024
#define H_ 8
#define E_ 64
#define SB 64
#define QB 128
#define NT 16
#define IMG_BYTES 32768
#define WS_NEEDED (64ull * NT * IMG_BYTES)   // 33.5 MB
#define C_EXP 0.18033688011112042f           // 0.125 * log2(e)

typedef float  f32x4  __attribute__((ext_vector_type(4)));
typedef float  f32x16 __attribute__((ext_vector_type(16)));
typedef __bf16 bf16x8 __attribute__((ext_vector_type(8)));
typedef unsigned short u16x8 __attribute__((ext_vector_type(8)));
typedef unsigned short u16x4 __attribute__((ext_vector_type(4)));
typedef unsigned int   u32x4 __attribute__((ext_vector_type(4)));

static __device__ __forceinline__ unsigned short f2b(float f) {
    __bf16 h = (__bf16)f;
    return __builtin_bit_cast(unsigned short, h);
}

static __device__ __forceinline__ float fsqrt_(float x) {
    return __builtin_amdgcn_sqrtf(x);          // v_sqrt_f32
}
static __device__ __forceinline__ float fexp2_(float x) {
    return __builtin_amdgcn_exp2f(x);          // v_exp_f32 (2^x)
}

static __device__ __forceinline__ u16x8 pack8(float4 a, float4 b) {
    u16x8 t;
    t[0]=f2b(a.x); t[1]=f2b(a.y); t[2]=f2b(a.z); t[3]=f2b(a.w);
    t[4]=f2b(b.x); t[5]=f2b(b.y); t[6]=f2b(b.z); t[7]=f2b(b.w);
    return t;
}

static __device__ __forceinline__ f32x16 mfma32(u16x8 a, u16x8 b, f32x16 c) {
    return __builtin_amdgcn_mfma_f32_32x32x16_bf16(
        __builtin_bit_cast(bf16x8, a), __builtin_bit_cast(bf16x8, b), c, 0, 0, 0);
}

static __device__ __forceinline__ unsigned int cvtpk(float lo, float hi) {
    unsigned int r;
    asm("v_cvt_pk_bf16_f32 %0, %1, %2" : "=v"(r) : "v"(lo), "v"(hi));
    return r;
}

static __device__ __forceinline__ void plswap(unsigned int& x, unsigned int& y) {
    asm("v_permlane32_swap_b32 %0, %1" : "+v"(x), "+v"(y));
}

static __device__ __forceinline__ u16x8 negbf8(u16x8 a) {
    u32x4 u = __builtin_bit_cast(u32x4, a);
    u[0] ^= 0x80008000u; u[1] ^= 0x80008000u; u[2] ^= 0x80008000u; u[3] ^= 0x80008000u;
    return __builtin_bit_cast(u16x8, u);
}

static __device__ __forceinline__ void gload16(const void* g, void* l) {
    __builtin_amdgcn_global_load_lds(
        (const __attribute__((address_space(1))) void*)g,
        (__attribute__((address_space(3))) void*)l,
        16, 0, 0);
}

// ---- QK for one 32-key half: 16 MFMAs, 2 accumulator chains (no setprio) ----
static __device__ __forceinline__ void qk_half(
    const u16x8 K[8], const u16x8 qre[4], const u16x8 qim[4], const u16x8 qimn[4],
    f32x16& sR, f32x16& sI)
{
    const f32x16 z16 = {};
    sR = mfma32(K[0], qre[0],  z16);
    sI = mfma32(K[1], qre[0],  z16);
    sR = mfma32(K[1], qimn[0], sR);
    sI = mfma32(K[0], qim[0],  sI);
    sR = mfma32(K[2], qre[1],  sR);
    sI = mfma32(K[3], qre[1],  sI);
    sR = mfma32(K[3], qimn[1], sR);
    sI = mfma32(K[2], qim[1],  sI);
    sR = mfma32(K[4], qre[2],  sR);
    sI = mfma32(K[5], qre[2],  sI);
    sR = mfma32(K[5], qimn[2], sR);
    sI = mfma32(K[4], qim[2],  sI);
    sR = mfma32(K[6], qre[3],  sR);
    sI = mfma32(K[7], qre[3],  sI);
    sR = mfma32(K[7], qimn[3], sR);
    sI = mfma32(K[6], qim[3],  sI);
}

// ---- softmax for one half: p = exp(0.125*|s|), fixed max 0; build PV A-frags ----
static __device__ __forceinline__ void sm_half(
    f32x16 sR, f32x16 sI, float& lsum, u16x8& pa0, u16x8& pa1)
{
    float p[16];
#pragma unroll
    for (int r = 0; r < 16; ++r) {
        float mag = fsqrt_(fmaf(sR[r], sR[r], sI[r] * sI[r]));
        p[r] = fexp2_(mag * C_EXP);
    }
    lsum += (((p[0]+p[1])+(p[2]+p[3])) + ((p[4]+p[5])+(p[6]+p[7])))
          + (((p[8]+p[9])+(p[10]+p[11])) + ((p[12]+p[13])+(p[14]+p[15])));

    unsigned int a0 = cvtpk(p[0],  p[1]),  a1 = cvtpk(p[4],  p[5]);
    unsigned int a2 = cvtpk(p[2],  p[3]),  a3 = cvtpk(p[6],  p[7]);
    unsigned int b0 = cvtpk(p[8],  p[9]),  b1 = cvtpk(p[12], p[13]);
    unsigned int b2 = cvtpk(p[10], p[11]), b3 = cvtpk(p[14], p[15]);
    plswap(a0, a1);
    plswap(a2, a3);
    plswap(b0, b1);
    plswap(b2, b3);
    u32x4 wa = {a0, a2, a1, a3};
    u32x4 wb = {b0, b2, b1, b3};
    pa0 = __builtin_bit_cast(u16x8, wa);
    pa1 = __builtin_bit_cast(u16x8, wb);
}

// ---- PV for one half: 8 MFMAs, V frags loaded just-in-time from LDS (no setprio) ----
static __device__ __forceinline__ void pv_half_lds(
    u16x8 pa0, u16x8 pa1, const char* vbase,
    f32x16& oR0, f32x16& oR1, f32x16& oI0, f32x16& oI1)
{
    u16x8 vf[8];
#pragma unroll
    for (int g = 0; g < 8; ++g)
        vf[g] = *(const u16x8*)(vbase + g * 1024);
    oR0 = mfma32(pa0, vf[0], oR0);
    oR1 = mfma32(pa0, vf[1], oR1);
    oI0 = mfma32(pa0, vf[2], oI0);
    oI1 = mfma32(pa0, vf[3], oI1);
    oR0 = mfma32(pa1, vf[4], oR0);
    oR1 = mfma32(pa1, vf[5], oR1);
    oI0 = mfma32(pa1, vf[6], oI0);
    oI1 = mfma32(pa1, vf[7], oI1);
}

// ---------------- pass 1: prepack K/V into fragment-ordered bf16 images ----------------
__global__ __launch_bounds__(256) void ffa_prepack(
    const float* __restrict__ k_re, const float* __restrict__ k_im,
    const float* __restrict__ v_re, const float* __restrict__ v_im,
    char* __restrict__ ws)
{
    const int tid = threadIdx.x;
    const int bh  = blockIdx.x >> 4;
    const int st  = blockIdx.x & 15;
    const int b   = bh >> 3;
    const int h   = bh & 7;
    const int s0  = st * SB;
    char* const img = ws + (size_t)blockIdx.x * IMG_BYTES;

    const int l   = tid & 63;
    const int fg  = tid >> 6;
    const int l31 = l & 31;
    const int lh  = l >> 5;

#pragma unroll
    for (int ff = 0; ff < 8; ++ff) {
        const int f = fg * 8 + ff;
        u16x8 val;
        if (f < 16) {
            const int kh = f >> 3, ks = (f >> 1) & 3, c = f & 1;
            const float* src = (c ? k_im : k_re)
                + ((size_t)((b * L_ + s0 + kh * 32 + l31) * H_ + h)) * E_ + ks * 16 + lh * 8;
            const float4* p = (const float4*)src;
            val = pack8(p[0], p[1]);
        } else {
            const int g = f - 16, ks = g >> 2, j = g & 3;
            const float* src = (j >= 2) ? v_im : v_re;
            const int d = (j & 1) * 32 + l31;
            const int sb = s0 + ks * 16 + lh * 8;
            float4 t0, t1;
            t0.x = src[((size_t)((b * L_ + sb + 0) * H_ + h)) * E_ + d];
            t0.y = src[((size_t)((b * L_ + sb + 1) * H_ + h)) * E_ + d];
            t0.z = src[((size_t)((b * L_ + sb + 2) * H_ + h)) * E_ + d];
            t0.w = src[((size_t)((b * L_ + sb + 3) * H_ + h)) * E_ + d];
            t1.x = src[((size_t)((b * L_ + sb + 4) * H_ + h)) * E_ + d];
            t1.y = src[((size_t)((b * L_ + sb + 5) * H_ + h)) * E_ + d];
            t1.z = src[((size_t)((b * L_ + sb + 6) * H_ + h)) * E_ + d];
            t1.w = src[((size_t)((b * L_ + sb + 7) * H_ + h)) * E_ + d];
            val = pack8(t0, t1);
        }
        *(u16x8*)(img + f * 1024 + l * 16) = val;
    }
}

// ---------------- pass 2: main flash kernel (256 thr, LDS dbuf, no setprio) ----------------
__global__ __launch_bounds__(256, 2) void ffa_main(
    const float* __restrict__ q_re, const float* __restrict__ q_im,
    const char* __restrict__ ws, float* __restrict__ out)
{
    __shared__ __align__(16) char Buf[2][IMG_BYTES];   // 64KB double-buffered tile image

    const int tid  = threadIdx.x;
    const int lane = tid & 63;
    const int w    = tid >> 6;          // wave 0..3
    const int l31  = lane & 31;
    const int h    = lane >> 5;

    // XCD-aware swizzle: grid 512 = 64 bh x 8 qblk
    const int work = (blockIdx.x & 7) * 64 + (blockIdx.x >> 3);
    const int bh   = work >> 3;
    const int qblk = work & 7;
    const int b    = bh >> 3;
    const int hh   = bh & 7;
    const char* const imgt = ws + (size_t)bh * (NT * IMG_BYTES);   // tile images base

    // ---- prologue: stage tile 0 into Buf[0] (cover: Q packing below) ----
#pragma unroll
    for (int j = 0; j < 8; ++j)
        gload16(imgt + j * 4096 + tid * 16, Buf[0] + j * 4096 + tid * 16);

    // ---- Q B-frags (col = l31 = q-row, k = 8h+i within each 16-kstep) ----
    u16x8 qre[4], qim[4], qimn[4];
    {
        const int qrow = qblk * QB + w * 32 + l31;
        const int base = ((b * L_ + qrow) * H_ + hh) * E_;
#pragma unroll
        for (int ks = 0; ks < 4; ++ks) {
            const float4* pr = (const float4*)(q_re + base + ks * 16 + h * 8);
            const float4* pi = (const float4*)(q_im + base + ks * 16 + h * 8);
            qre[ks]  = pack8(pr[0], pr[1]);
            qim[ks]  = pack8(pi[0], pi[1]);
            qimn[ks] = negbf8(qim[ks]);
        }
    }

    f32x16 oR0 = {}, oR1 = {}, oI0 = {}, oI1 = {};
    float lsum = 0.f;

    asm volatile("s_waitcnt vmcnt(0)" ::: "memory");
    __syncthreads();

    for (int t = 0; t < NT; ++t) {
        const int cur = t & 1;
        // ---- stage next tile into the other buffer (cover: this tile's compute) ----
        if (t + 1 < NT) {
            const char* src = imgt + (size_t)(t + 1) * IMG_BYTES;
            char* dst = Buf[cur ^ 1];
#pragma unroll
            for (int j = 0; j < 8; ++j)
                gload16(src + j * 4096 + tid * 16, dst + j * 4096 + tid * 16);
        }
        const char* const kb = Buf[cur] + lane * 16;   // fragment f at kb + f*1024

        // ---- both QK blocks back-to-back (4 independent chains); K frags die inside ----
        f32x16 sR0, sI0, sR1, sI1;
        {
            u16x8 kf[8];
#pragma unroll
            for (int j = 0; j < 8; ++j)
                kf[j] = *(const u16x8*)(kb + j * 1024);
            qk_half(kf, qre, qim, qimn, sR0, sI0);
        }
        {
            u16x8 kf[8];
#pragma unroll
            for (int j = 0; j < 8; ++j)
                kf[j] = *(const u16x8*)(kb + 8192 + j * 1024);
            qk_half(kf, qre, qim, qimn, sR1, sI1);   // issues under h0's chain latency
        }

        // ---- SM(h0) runs under QK(h1)'s MFMA drain; V frags just-in-time ----
        {
            u16x8 pa0, pa1;
            sm_half(sR0, sI0, lsum, pa0, pa1);
            pv_half_lds(pa0, pa1, kb + 16 * 1024, oR0, oR1, oI0, oI1);
        }
        {
            u16x8 pa0, pa1;
            sm_half(sR1, sI1, lsum, pa0, pa1);
            pv_half_lds(pa0, pa1, kb + 24 * 1024, oR0, oR1, oI0, oI1);
        }

        asm volatile("s_waitcnt vmcnt(0)" ::: "memory");   // next tile staged
        __syncthreads();
    }

    // ---- epilogue: combine half-lane lsums, normalize, write (re,im) pairs ----
    lsum += __shfl_xor(lsum, 32);
    const float inv = 1.0f / lsum;      // lane (l31, h): inv for q-row l31
#pragma unroll
    for (int r = 0; r < 16; ++r) {
        const int qs = (r & 3) + 8 * (r >> 2) + 4 * h;   // q-row of O reg r
        const float iv = __shfl(inv, qs);
        const int lq = qblk * QB + w * 32 + qs;
        float* op = out + ((b * L_ + lq) * H_ + hh) * (E_ * 2);
        float2 v0 = make_float2(oR0[r] * iv, oI0[r] * iv);
        float2 v1 = make_float2(oR1[r] * iv, oI1[r] * iv);
        *(float2*)(op + l31 * 2)      = v0;
        *(float2*)(op + 64 + l31 * 2) = v1;
    }
}

// ---------------- fallback (round-2 structure) if ws is too small ----------------
__global__ __launch_bounds__(256) void ffa_fwd_fb(
    const float* __restrict__ q_re, const float* __restrict__ q_im,
    const float* __restrict__ k_re, const float* __restrict__ k_im,
    const float* __restrict__ v_re, const float* __restrict__ v_im,
    float* __restrict__ out)
{
    __shared__ __align__(16) unsigned short Kt[64 * 128];
    __shared__ __align__(16) unsigned short Vt[128 * 64];
    __shared__ __align__(16) unsigned short Pw[4 * 16 * 64];
    char* const kb = (char*)Kt;
    char* const vb = (char*)Vt;

    const int tid  = threadIdx.x;
    const int lane = tid & 63;
    const int w    = tid >> 6;
    const int lr   = lane & 15;
    const int lg   = lane >> 4;
    const int lg16 = lg * 16;
    const int qblk = blockIdx.x & 15;
    const int bh   = blockIdx.x >> 4;
    const int b    = bh >> 3;
    const int h    = bh & 7;

    u16x8 qre[2], qim[2], qimn[2];
    {
        const int qrow = qblk * 64 + w * 16 + lr;
        const int base = ((b * L_ + qrow) * H_ + h) * E_ + lg * 8;
#pragma unroll
        for (int ks = 0; ks < 2; ++ks) {
            const float4* pr = (const float4*)(q_re + base + ks * 32);
            const float4* pi = (const float4*)(q_im + base + ks * 32);
            qre[ks] = pack8(pr[0], pr[1]);
            qim[ks] = pack8(pi[0], pi[1]);
#pragma unroll
            for (int i = 0; i < 8; ++i)
                qimn[ks][i] = (unsigned short)(qim[ks][i] ^ 0x8000u);
        }
    }

    float lsum[4];
    f32x4 Ore[4], Oim[4];
    const f32x4 zero = {0.f, 0.f, 0.f, 0.f};
#pragma unroll
    for (int r = 0; r < 4; ++r) lsum[r] = 0.f;
#pragma unroll
    for (int dt = 0; dt < 4; ++dt) { Ore[dt] = zero; Oim[dt] = zero; }

    const int sr = tid >> 2;
    const int sc = (tid & 3) * 16;
    const int vtens = tid >> 7;
    const int vd    = ((tid >> 4) & 7) * 8;
    const int vs    = (tid & 15) * 4;
    const float* const vsrc = vtens ? v_im : v_re;

    for (int st = 0; st < L_ / SB; ++st) {
        const int s0 = st * SB;
        {
            const int kg = ((b * L_ + s0 + sr) * H_ + h) * E_ + sc;
            const float4* pr = (const float4*)(k_re + kg);
            const float4* pi = (const float4*)(k_im + kg);
            float4 r0 = pr[0], r1 = pr[1], r2 = pr[2], r3 = pr[3];
            float4 i0 = pi[0], i1 = pi[1], i2 = pi[2], i3 = pi[3];
            const int krow = sr * 256;
            const int ksw  = (sr & 7) << 4;
            *(u16x8*)(kb + ((krow + sc * 2           ) ^ ksw)) = pack8(r0, r1);
            *(u16x8*)(kb + ((krow + sc * 2 + 16      ) ^ ksw)) = pack8(r2, r3);
            *(u16x8*)(kb + ((krow + 128 + sc * 2     ) ^ ksw)) = pack8(i0, i1);
            *(u16x8*)(kb + ((krow + 128 + sc * 2 + 16) ^ ksw)) = pack8(i2, i3);
        }
        {
            float vv[4][8];
#pragma unroll
            for (int j = 0; j < 4; ++j) {
                const float4* p = (const float4*)(vsrc + ((b * L_ + s0 + vs + j) * H_ + h) * E_ + vd);
                float4 x = p[0], y = p[1];
                vv[j][0]=x.x; vv[j][1]=x.y; vv[j][2]=x.z; vv[j][3]=x.w;
                vv[j][4]=y.x; vv[j][5]=y.y; vv[j][6]=y.z; vv[j][7]=y.w;
            }
#pragma unroll
            for (int i = 0; i < 8; ++i) {
                const int row = vtens * 64 + vd + i;
                u16x4 t;
                t[0]=f2b(vv[0][i]); t[1]=f2b(vv[1][i]); t[2]=f2b(vv[2][i]); t[3]=f2b(vv[3][i]);
                *(u16x4*)(vb + ((row * 128 + vs * 2) ^ ((row & 7) << 4))) = t;
            }
        }
        __syncthreads();

        f32x4 aR[4], aI[4];
#pragma unroll
        for (int t = 0; t < 4; ++t) { aR[t] = zero; aI[t] = zero; }
#pragma unroll
        for (int t = 0; t < 4; ++t) {
            const int key = t * 16 + lr;
            const char* kr = kb + key * 256;
            const int sw = (key & 7) << 4;
            u16x8 br0 = *(const u16x8*)(kr + (( lg16      ) ^ sw));
            u16x8 br1 = *(const u16x8*)(kr + (( 64 + lg16 ) ^ sw));
            u16x8 bi0 = *(const u16x8*)(kr + ((128 + lg16 ) ^ sw));
            u16x8 bi1 = *(const u16x8*)(kr + ((192 + lg16 ) ^ sw));
            aR[t] = __builtin_amdgcn_mfma_f32_16x16x32_bf16(__builtin_bit_cast(bf16x8,qre[0]),  __builtin_bit_cast(bf16x8,br0), aR[t],0,0,0);
            aR[t] = __builtin_amdgcn_mfma_f32_16x16x32_bf16(__builtin_bit_cast(bf16x8,qre[1]),  __builtin_bit_cast(bf16x8,br1), aR[t],0,0,0);
            aR[t] = __builtin_amdgcn_mfma_f32_16x16x32_bf16(__builtin_bit_cast(bf16x8,qimn[0]), __builtin_bit_cast(bf16x8,bi0), aR[t],0,0,0);
            aR[t] = __builtin_amdgcn_mfma_f32_16x16x32_bf16(__builtin_bit_cast(bf16x8,qimn[1]), __builtin_bit_cast(bf16x8,bi1), aR[t],0,0,0);
            aI[t] = __builtin_amdgcn_mfma_f32_16x16x32_bf16(__builtin_bit_cast(bf16x8,qre[0]),  __builtin_bit_cast(bf16x8,bi0), aI[t],0,0,0);
            aI[t] = __builtin_amdgcn_mfma_f32_16x16x32_bf16(__builtin_bit_cast(bf16x8,qre[1]),  __builtin_bit_cast(bf16x8,bi1), aI[t],0,0,0);
            aI[t] = __builtin_amdgcn_mfma_f32_16x16x32_bf16(__builtin_bit_cast(bf16x8,qim[0]),  __builtin_bit_cast(bf16x8,br0), aI[t],0,0,0);
            aI[t] = __builtin_amdgcn_mfma_f32_16x16x32_bf16(__builtin_bit_cast(bf16x8,qim[1]),  __builtin_bit_cast(bf16x8,br1), aI[t],0,0,0);
        }

        float p_[4][4];
#pragma unroll
        for (int t = 0; t < 4; ++t)
#pragma unroll
            for (int r = 0; r < 4; ++r) {
                float re = aR[t][r], im = aI[t][r];
                p_[t][r] = fexp2_(fsqrt_(fmaf(re, re, im * im)) * C_EXP);
            }
#pragma unroll
        for (int r = 0; r < 4; ++r)
            lsum[r] += (p_[0][r] + p_[1][r]) + (p_[2][r] + p_[3][r]);

        char* const pb = (char*)Pw + w * 2048;
#pragma unroll
        for (int t = 0; t < 4; ++t)
#pragma unroll
            for (int r = 0; r < 4; ++r) {
                const int prow = lg * 4 + r;
                *(unsigned short*)(pb + ((prow * 128 + (t * 16 + lr) * 2) ^ ((prow & 7) << 4)))
                    = f2b(p_[t][r]);
            }
        asm volatile("s_waitcnt lgkmcnt(0)" ::: "memory");
        __builtin_amdgcn_sched_barrier(0);
        const int psw = (lr & 7) << 4;
        u16x8 pf0 = *(const u16x8*)(pb + ((lr * 128 + lg16     ) ^ psw));
        u16x8 pf1 = *(const u16x8*)(pb + ((lr * 128 + 64 + lg16) ^ psw));

#pragma unroll
        for (int dt = 0; dt < 4; ++dt) {
            const int dr = dt * 16 + lr;
            const int swr = (dr & 7) << 4;
            const char* vrre = vb + dr * 128;
            const char* vrim = vb + (64 + dr) * 128;
            u16x8 vr0 = *(const u16x8*)(vrre + (( lg16     ) ^ swr));
            u16x8 vr1 = *(const u16x8*)(vrre + (( 64 + lg16) ^ swr));
            u16x8 vi0 = *(const u16x8*)(vrim + (( lg16     ) ^ swr));
            u16x8 vi1 = *(const u16x8*)(vrim + (( 64 + lg16) ^ swr));
            Ore[dt] = __builtin_amdgcn_mfma_f32_16x16x32_bf16(__builtin_bit_cast(bf16x8,pf0), __builtin_bit_cast(bf16x8,vr0), Ore[dt],0,0,0);
            Ore[dt] = __builtin_amdgcn_mfma_f32_16x16x32_bf16(__builtin_bit_cast(bf16x8,pf1), __builtin_bit_cast(bf16x8,vr1), Ore[dt],0,0,0);
            Oim[dt] = __builtin_amdgcn_mfma_f32_16x16x32_bf16(__builtin_bit_cast(bf16x8,pf0), __builtin_bit_cast(bf16x8,vi0), Oim[dt],0,0,0);
            Oim[dt] = __builtin_amdgcn_mfma_f32_16x16x32_bf16(__builtin_bit_cast(bf16x8,pf1), __builtin_bit_cast(bf16x8,vi1), Oim[dt],0,0,0);
        }
        __syncthreads();
    }

#pragma unroll
    for (int r = 0; r < 4; ++r) {
        float s = lsum[r];
        s += __shfl_xor(s, 1);
        s += __shfl_xor(s, 2);
        s += __shfl_xor(s, 4);
        s += __shfl_xor(s, 8);
        const float inv = 1.0f / s;
        const int lq = qblk * 64 + w * 16 + lg * 4 + r;
        const int obase = (((b * L_ + lq) * H_ + h) * E_) * 2;
#pragma unroll
        for (int dt = 0; dt < 4; ++dt) {
            const int d = dt * 16 + lr;
            float2 val = make_float2(Ore[dt][r] * inv, Oim[dt][r] * inv);
            *(float2*)(out + obase + d * 2) = val;
        }
    }
}

extern "C" void kernel_launch(void* const* d_in, const int* in_sizes, int n_in,
                              void* d_out, int out_size, void* d_ws, size_t ws_size,
                              hipStream_t stream) {
    const float* q_re = (const float*)d_in[0];
    const float* q_im = (const float*)d_in[1];
    const float* k_re = (const float*)d_in[2];
    const float* k_im = (const float*)d_in[3];
    const float* v_re = (const float*)d_in[4];
    const float* v_im = (const float*)d_in[5];
    float* out = (float*)d_out;

    if (ws_size >= WS_NEEDED) {
        char* ws = (char*)d_ws;
        hipLaunchKernelGGL(ffa_prepack, dim3(B_ * H_ * NT), dim3(256), 0, stream,
                           k_re, k_im, v_re, v_im, ws);
        hipLaunchKernelGGL(ffa_main, dim3(B_ * H_ * (L_ / QB)), dim3(256), 0, stream,
                           q_re, q_im, (const char*)ws, out);
    } else {
        hipLaunchKernelGGL(ffa_fwd_fb, dim3(B_ * H_ * (L_ / 64)), dim3(256), 0, stream,
                           q_re, q_im, k_re, k_im, v_re, v_im, out);
    }
}

// Round 18
// 80.017 us; speedup vs baseline: 1.0245x; 1.0245x over previous
//
#include <hip/hip_runtime.h>

// FullFreqAttention: B=8, L=S=1024, H=8, E=D=64
// scores = complex QK^T (no conj); A = softmax(0.125*|scores|); out = stack(A@v_re, A@v_im)
//
// Pass 1: prepack K/V -> bf16 FRAGMENT-ORDERED tile images in d_ws. K is PRE-SCALED by
//   0.125*log2(e) so the softmax scale multiply vanishes from the hot path
//   (|c*z| = c*|z|; fp32 MFMA accumulation, precision unchanged).
// Pass 2: flash kernel, 4 waves x 32 q-rows (QB=128, grid 512). Full 32KB tile staged
//   into LDS (global_load_lds w16, double-buffered 64KB). Dual-QK ILP (both halves'
//   QK back-to-back, 4 independent score chains), V frags just-in-time from LDS.
//   No s_setprio (hurts lockstep structures, r17 A/B). Swapped-operand 32x32x16 MFMA,
//   in-register softmax (v_cvt_pk_bf16_f32 + v_permlane32_swap_b32), fixed max = 0.

#define B_ 8
#define L_ 1024
#define H_ 8
#define E_ 64
#define SB 64
#define QB 128
#define NT 16
#define IMG_BYTES 32768
#define WS_NEEDED (64ull * NT * IMG_BYTES)   // 33.5 MB
#define C_EXP 0.18033688011112042f           // 0.125 * log2(e)

typedef float  f32x4  __attribute__((ext_vector_type(4)));
typedef float  f32x16 __attribute__((ext_vector_type(16)));
typedef __bf16 bf16x8 __attribute__((ext_vector_type(8)));
typedef unsigned short u16x8 __attribute__((ext_vector_type(8)));
typedef unsigned short u16x4 __attribute__((ext_vector_type(4)));
typedef unsigned int   u32x4 __attribute__((ext_vector_type(4)));

static __device__ __forceinline__ unsigned short f2b(float f) {
    __bf16 h = (__bf16)f;
    return __builtin_bit_cast(unsigned short, h);
}

static __device__ __forceinline__ float fsqrt_(float x) {
    return __builtin_amdgcn_sqrtf(x);          // v_sqrt_f32
}
static __device__ __forceinline__ float fexp2_(float x) {
    return __builtin_amdgcn_exp2f(x);          // v_exp_f32 (2^x)
}

static __device__ __forceinline__ u16x8 pack8(float4 a, float4 b) {
    u16x8 t;
    t[0]=f2b(a.x); t[1]=f2b(a.y); t[2]=f2b(a.z); t[3]=f2b(a.w);
    t[4]=f2b(b.x); t[5]=f2b(b.y); t[6]=f2b(b.z); t[7]=f2b(b.w);
    return t;
}

static __device__ __forceinline__ u16x8 pack8s(float4 a, float4 b, float s) {
    u16x8 t;
    t[0]=f2b(a.x*s); t[1]=f2b(a.y*s); t[2]=f2b(a.z*s); t[3]=f2b(a.w*s);
    t[4]=f2b(b.x*s); t[5]=f2b(b.y*s); t[6]=f2b(b.z*s); t[7]=f2b(b.w*s);
    return t;
}

static __device__ __forceinline__ f32x16 mfma32(u16x8 a, u16x8 b, f32x16 c) {
    return __builtin_amdgcn_mfma_f32_32x32x16_bf16(
        __builtin_bit_cast(bf16x8, a), __builtin_bit_cast(bf16x8, b), c, 0, 0, 0);
}

static __device__ __forceinline__ unsigned int cvtpk(float lo, float hi) {
    unsigned int r;
    asm("v_cvt_pk_bf16_f32 %0, %1, %2" : "=v"(r) : "v"(lo), "v"(hi));
    return r;
}

static __device__ __forceinline__ void plswap(unsigned int& x, unsigned int& y) {
    asm("v_permlane32_swap_b32 %0, %1" : "+v"(x), "+v"(y));
}

static __device__ __forceinline__ u16x8 negbf8(u16x8 a) {
    u32x4 u = __builtin_bit_cast(u32x4, a);
    u[0] ^= 0x80008000u; u[1] ^= 0x80008000u; u[2] ^= 0x80008000u; u[3] ^= 0x80008000u;
    return __builtin_bit_cast(u16x8, u);
}

static __device__ __forceinline__ void gload16(const void* g, void* l) {
    __builtin_amdgcn_global_load_lds(
        (const __attribute__((address_space(1))) void*)g,
        (__attribute__((address_space(3))) void*)l,
        16, 0, 0);
}

// ---- QK for one 32-key half: 16 MFMAs, 2 accumulator chains ----
static __device__ __forceinline__ void qk_half(
    const u16x8 K[8], const u16x8 qre[4], const u16x8 qim[4], const u16x8 qimn[4],
    f32x16& sR, f32x16& sI)
{
    const f32x16 z16 = {};
    sR = mfma32(K[0], qre[0],  z16);
    sI = mfma32(K[1], qre[0],  z16);
    sR = mfma32(K[1], qimn[0], sR);
    sI = mfma32(K[0], qim[0],  sI);
    sR = mfma32(K[2], qre[1],  sR);
    sI = mfma32(K[3], qre[1],  sI);
    sR = mfma32(K[3], qimn[1], sR);
    sI = mfma32(K[2], qim[1],  sI);
    sR = mfma32(K[4], qre[2],  sR);
    sI = mfma32(K[5], qre[2],  sI);
    sR = mfma32(K[5], qimn[2], sR);
    sI = mfma32(K[4], qim[2],  sI);
    sR = mfma32(K[6], qre[3],  sR);
    sI = mfma32(K[7], qre[3],  sI);
    sR = mfma32(K[7], qimn[3], sR);
    sI = mfma32(K[6], qim[3],  sI);
}

// ---- softmax for one half: p = exp2(|s'|) with pre-scaled scores; build PV A-frags ----
static __device__ __forceinline__ void sm_half(
    f32x16 sR, f32x16 sI, float& lsum, u16x8& pa0, u16x8& pa1)
{
    float p[16];
#pragma unroll
    for (int r = 0; r < 16; ++r) {
        float mag = fsqrt_(fmaf(sR[r], sR[r], sI[r] * sI[r]));
        p[r] = fexp2_(mag);
    }
    lsum += (((p[0]+p[1])+(p[2]+p[3])) + ((p[4]+p[5])+(p[6]+p[7])))
          + (((p[8]+p[9])+(p[10]+p[11])) + ((p[12]+p[13])+(p[14]+p[15])));

    unsigned int a0 = cvtpk(p[0],  p[1]),  a1 = cvtpk(p[4],  p[5]);
    unsigned int a2 = cvtpk(p[2],  p[3]),  a3 = cvtpk(p[6],  p[7]);
    unsigned int b0 = cvtpk(p[8],  p[9]),  b1 = cvtpk(p[12], p[13]);
    unsigned int b2 = cvtpk(p[10], p[11]), b3 = cvtpk(p[14], p[15]);
    plswap(a0, a1);
    plswap(a2, a3);
    plswap(b0, b1);
    plswap(b2, b3);
    u32x4 wa = {a0, a2, a1, a3};
    u32x4 wb = {b0, b2, b1, b3};
    pa0 = __builtin_bit_cast(u16x8, wa);
    pa1 = __builtin_bit_cast(u16x8, wb);
}

// ---- PV for one half: 8 MFMAs, V frags loaded just-in-time from LDS ----
static __device__ __forceinline__ void pv_half_lds(
    u16x8 pa0, u16x8 pa1, const char* vbase,
    f32x16& oR0, f32x16& oR1, f32x16& oI0, f32x16& oI1)
{
    u16x8 vf[8];
#pragma unroll
    for (int g = 0; g < 8; ++g)
        vf[g] = *(const u16x8*)(vbase + g * 1024);
    oR0 = mfma32(pa0, vf[0], oR0);
    oR1 = mfma32(pa0, vf[1], oR1);
    oI0 = mfma32(pa0, vf[2], oI0);
    oI1 = mfma32(pa0, vf[3], oI1);
    oR0 = mfma32(pa1, vf[4], oR0);
    oR1 = mfma32(pa1, vf[5], oR1);
    oI0 = mfma32(pa1, vf[6], oI0);
    oI1 = mfma32(pa1, vf[7], oI1);
}

// ---------------- pass 1: prepack K/V into fragment-ordered bf16 images ----------------
__global__ __launch_bounds__(256) void ffa_prepack(
    const float* __restrict__ k_re, const float* __restrict__ k_im,
    const float* __restrict__ v_re, const float* __restrict__ v_im,
    char* __restrict__ ws)
{
    const int tid = threadIdx.x;
    const int bh  = blockIdx.x >> 4;
    const int st  = blockIdx.x & 15;
    const int b   = bh >> 3;
    const int h   = bh & 7;
    const int s0  = st * SB;
    char* const img = ws + (size_t)blockIdx.x * IMG_BYTES;

    const int l   = tid & 63;
    const int fg  = tid >> 6;
    const int l31 = l & 31;
    const int lh  = l >> 5;

#pragma unroll
    for (int ff = 0; ff < 8; ++ff) {
        const int f = fg * 8 + ff;
        u16x8 val;
        if (f < 16) {
            const int kh = f >> 3, ks = (f >> 1) & 3, c = f & 1;
            const float* src = (c ? k_im : k_re)
                + ((size_t)((b * L_ + s0 + kh * 32 + l31) * H_ + h)) * E_ + ks * 16 + lh * 8;
            const float4* p = (const float4*)src;
            val = pack8s(p[0], p[1], C_EXP);   // K pre-scaled: |c*z| = c*|z|
        } else {
            const int g = f - 16, ks = g >> 2, j = g & 3;
            const float* src = (j >= 2) ? v_im : v_re;
            const int d = (j & 1) * 32 + l31;
            const int sb = s0 + ks * 16 + lh * 8;
            float4 t0, t1;
            t0.x = src[((size_t)((b * L_ + sb + 0) * H_ + h)) * E_ + d];
            t0.y = src[((size_t)((b * L_ + sb + 1) * H_ + h)) * E_ + d];
            t0.z = src[((size_t)((b * L_ + sb + 2) * H_ + h)) * E_ + d];
            t0.w = src[((size_t)((b * L_ + sb + 3) * H_ + h)) * E_ + d];
            t1.x = src[((size_t)((b * L_ + sb + 4) * H_ + h)) * E_ + d];
            t1.y = src[((size_t)((b * L_ + sb + 5) * H_ + h)) * E_ + d];
            t1.z = src[((size_t)((b * L_ + sb + 6) * H_ + h)) * E_ + d];
            t1.w = src[((size_t)((b * L_ + sb + 7) * H_ + h)) * E_ + d];
            val = pack8(t0, t1);
        }
        *(u16x8*)(img + f * 1024 + l * 16) = val;
    }
}

// ---------------- pass 2: main flash kernel (256 thr, LDS dbuf) ----------------
__global__ __launch_bounds__(256, 2) void ffa_main(
    const float* __restrict__ q_re, const float* __restrict__ q_im,
    const char* __restrict__ ws, float* __restrict__ out)
{
    __shared__ __align__(16) char Buf[2][IMG_BYTES];   // 64KB double-buffered tile image

    const int tid  = threadIdx.x;
    const int lane = tid & 63;
    const int w    = tid >> 6;          // wave 0..3
    const int l31  = lane & 31;
    const int h    = lane >> 5;

    // XCD-aware swizzle: grid 512 = 64 bh x 8 qblk
    const int work = (blockIdx.x & 7) * 64 + (blockIdx.x >> 3);
    const int bh   = work >> 3;
    const int qblk = work & 7;
    const int b    = bh >> 3;
    const int hh   = bh & 7;
    const char* const imgt = ws + (size_t)bh * (NT * IMG_BYTES);   // tile images base

    // ---- prologue: stage tile 0 into Buf[0] (cover: Q packing below) ----
#pragma unroll
    for (int j = 0; j < 8; ++j)
        gload16(imgt + j * 4096 + tid * 16, Buf[0] + j * 4096 + tid * 16);

    // ---- Q B-frags (col = l31 = q-row, k = 8h+i within each 16-kstep) ----
    u16x8 qre[4], qim[4], qimn[4];
    {
        const int qrow = qblk * QB + w * 32 + l31;
        const int base = ((b * L_ + qrow) * H_ + hh) * E_;
#pragma unroll
        for (int ks = 0; ks < 4; ++ks) {
            const float4* pr = (const float4*)(q_re + base + ks * 16 + h * 8);
            const float4* pi = (const float4*)(q_im + base + ks * 16 + h * 8);
            qre[ks]  = pack8(pr[0], pr[1]);
            qim[ks]  = pack8(pi[0], pi[1]);
            qimn[ks] = negbf8(qim[ks]);
        }
    }

    f32x16 oR0 = {}, oR1 = {}, oI0 = {}, oI1 = {};
    float lsum = 0.f;

    asm volatile("s_waitcnt vmcnt(0)" ::: "memory");
    __syncthreads();

    for (int t = 0; t < NT; ++t) {
        const int cur = t & 1;
        // ---- stage next tile into the other buffer (cover: this tile's compute) ----
        if (t + 1 < NT) {
            const char* src = imgt + (size_t)(t + 1) * IMG_BYTES;
            char* dst = Buf[cur ^ 1];
#pragma unroll
            for (int j = 0; j < 8; ++j)
                gload16(src + j * 4096 + tid * 16, dst + j * 4096 + tid * 16);
        }
        const char* const kb = Buf[cur] + lane * 16;   // fragment f at kb + f*1024

        // ---- both QK blocks back-to-back (4 independent chains); K frags die inside ----
        f32x16 sR0, sI0, sR1, sI1;
        {
            u16x8 kf[8];
#pragma unroll
            for (int j = 0; j < 8; ++j)
                kf[j] = *(const u16x8*)(kb + j * 1024);
            qk_half(kf, qre, qim, qimn, sR0, sI0);
        }
        {
            u16x8 kf[8];
#pragma unroll
            for (int j = 0; j < 8; ++j)
                kf[j] = *(const u16x8*)(kb + 8192 + j * 1024);
            qk_half(kf, qre, qim, qimn, sR1, sI1);   // issues under h0's chain latency
        }

        // ---- SM(h0) runs under QK(h1)'s MFMA drain; V frags just-in-time ----
        {
            u16x8 pa0, pa1;
            sm_half(sR0, sI0, lsum, pa0, pa1);
            pv_half_lds(pa0, pa1, kb + 16 * 1024, oR0, oR1, oI0, oI1);
        }
        {
            u16x8 pa0, pa1;
            sm_half(sR1, sI1, lsum, pa0, pa1);
            pv_half_lds(pa0, pa1, kb + 24 * 1024, oR0, oR1, oI0, oI1);
        }

        asm volatile("s_waitcnt vmcnt(0)" ::: "memory");   // next tile staged
        __syncthreads();
    }

    // ---- epilogue: combine half-lane lsums, normalize, write (re,im) pairs ----
    lsum += __shfl_xor(lsum, 32);
    const float inv = 1.0f / lsum;      // lane (l31, h): inv for q-row l31
#pragma unroll
    for (int r = 0; r < 16; ++r) {
        const int qs = (r & 3) + 8 * (r >> 2) + 4 * h;   // q-row of O reg r
        const float iv = __shfl(inv, qs);
        const int lq = qblk * QB + w * 32 + qs;
        float* op = out + ((b * L_ + lq) * H_ + hh) * (E_ * 2);
        float2 v0 = make_float2(oR0[r] * iv, oI0[r] * iv);
        float2 v1 = make_float2(oR1[r] * iv, oI1[r] * iv);
        *(float2*)(op + l31 * 2)      = v0;
        *(float2*)(op + 64 + l31 * 2) = v1;
    }
}

// ---------------- fallback (round-2 structure) if ws is too small ----------------
__global__ __launch_bounds__(256) void ffa_fwd_fb(
    const float* __restrict__ q_re, const float* __restrict__ q_im,
    const float* __restrict__ k_re, const float* __restrict__ k_im,
    const float* __restrict__ v_re, const float* __restrict__ v_im,
    float* __restrict__ out)
{
    __shared__ __align__(16) unsigned short Kt[64 * 128];
    __shared__ __align__(16) unsigned short Vt[128 * 64];
    __shared__ __align__(16) unsigned short Pw[4 * 16 * 64];
    char* const kb = (char*)Kt;
    char* const vb = (char*)Vt;

    const int tid  = threadIdx.x;
    const int lane = tid & 63;
    const int w    = tid >> 6;
    const int lr   = lane & 15;
    const int lg   = lane >> 4;
    const int lg16 = lg * 16;
    const int qblk = blockIdx.x & 15;
    const int bh   = blockIdx.x >> 4;
    const int b    = bh >> 3;
    const int h    = bh & 7;

    u16x8 qre[2], qim[2], qimn[2];
    {
        const int qrow = qblk * 64 + w * 16 + lr;
        const int base = ((b * L_ + qrow) * H_ + h) * E_ + lg * 8;
#pragma unroll
        for (int ks = 0; ks < 2; ++ks) {
            const float4* pr = (const float4*)(q_re + base + ks * 32);
            const float4* pi = (const float4*)(q_im + base + ks * 32);
            qre[ks] = pack8(pr[0], pr[1]);
            qim[ks] = pack8(pi[0], pi[1]);
#pragma unroll
            for (int i = 0; i < 8; ++i)
                qimn[ks][i] = (unsigned short)(qim[ks][i] ^ 0x8000u);
        }
    }

    float lsum[4];
    f32x4 Ore[4], Oim[4];
    const f32x4 zero = {0.f, 0.f, 0.f, 0.f};
#pragma unroll
    for (int r = 0; r < 4; ++r) lsum[r] = 0.f;
#pragma unroll
    for (int dt = 0; dt < 4; ++dt) { Ore[dt] = zero; Oim[dt] = zero; }

    const int sr = tid >> 2;
    const int sc = (tid & 3) * 16;
    const int vtens = tid >> 7;
    const int vd    = ((tid >> 4) & 7) * 8;
    const int vs    = (tid & 15) * 4;
    const float* const vsrc = vtens ? v_im : v_re;

    for (int st = 0; st < L_ / SB; ++st) {
        const int s0 = st * SB;
        {
            const int kg = ((b * L_ + s0 + sr) * H_ + h) * E_ + sc;
            const float4* pr = (const float4*)(k_re + kg);
            const float4* pi = (const float4*)(k_im + kg);
            float4 r0 = pr[0], r1 = pr[1], r2 = pr[2], r3 = pr[3];
            float4 i0 = pi[0], i1 = pi[1], i2 = pi[2], i3 = pi[3];
            const int krow = sr * 256;
            const int ksw  = (sr & 7) << 4;
            *(u16x8*)(kb + ((krow + sc * 2           ) ^ ksw)) = pack8(r0, r1);
            *(u16x8*)(kb + ((krow + sc * 2 + 16      ) ^ ksw)) = pack8(r2, r3);
            *(u16x8*)(kb + ((krow + 128 + sc * 2     ) ^ ksw)) = pack8(i0, i1);
            *(u16x8*)(kb + ((krow + 128 + sc * 2 + 16) ^ ksw)) = pack8(i2, i3);
        }
        {
            float vv[4][8];
#pragma unroll
            for (int j = 0; j < 4; ++j) {
                const float4* p = (const float4*)(vsrc + ((b * L_ + s0 + vs + j) * H_ + h) * E_ + vd);
                float4 x = p[0], y = p[1];
                vv[j][0]=x.x; vv[j][1]=x.y; vv[j][2]=x.z; vv[j][3]=x.w;
                vv[j][4]=y.x; vv[j][5]=y.y; vv[j][6]=y.z; vv[j][7]=y.w;
            }
#pragma unroll
            for (int i = 0; i < 8; ++i) {
                const int row = vtens * 64 + vd + i;
                u16x4 t;
                t[0]=f2b(vv[0][i]); t[1]=f2b(vv[1][i]); t[2]=f2b(vv[2][i]); t[3]=f2b(vv[3][i]);
                *(u16x4*)(vb + ((row * 128 + vs * 2) ^ ((row & 7) << 4))) = t;
            }
        }
        __syncthreads();

        f32x4 aR[4], aI[4];
#pragma unroll
        for (int t = 0; t < 4; ++t) { aR[t] = zero; aI[t] = zero; }
#pragma unroll
        for (int t = 0; t < 4; ++t) {
            const int key = t * 16 + lr;
            const char* kr = kb + key * 256;
            const int sw = (key & 7) << 4;
            u16x8 br0 = *(const u16x8*)(kr + (( lg16      ) ^ sw));
            u16x8 br1 = *(const u16x8*)(kr + (( 64 + lg16 ) ^ sw));
            u16x8 bi0 = *(const u16x8*)(kr + ((128 + lg16 ) ^ sw));
            u16x8 bi1 = *(const u16x8*)(kr + ((192 + lg16 ) ^ sw));
            aR[t] = __builtin_amdgcn_mfma_f32_16x16x32_bf16(__builtin_bit_cast(bf16x8,qre[0]),  __builtin_bit_cast(bf16x8,br0), aR[t],0,0,0);
            aR[t] = __builtin_amdgcn_mfma_f32_16x16x32_bf16(__builtin_bit_cast(bf16x8,qre[1]),  __builtin_bit_cast(bf16x8,br1), aR[t],0,0,0);
            aR[t] = __builtin_amdgcn_mfma_f32_16x16x32_bf16(__builtin_bit_cast(bf16x8,qimn[0]), __builtin_bit_cast(bf16x8,bi0), aR[t],0,0,0);
            aR[t] = __builtin_amdgcn_mfma_f32_16x16x32_bf16(__builtin_bit_cast(bf16x8,qimn[1]), __builtin_bit_cast(bf16x8,bi1), aR[t],0,0,0);
            aI[t] = __builtin_amdgcn_mfma_f32_16x16x32_bf16(__builtin_bit_cast(bf16x8,qre[0]),  __builtin_bit_cast(bf16x8,bi0), aI[t],0,0,0);
            aI[t] = __builtin_amdgcn_mfma_f32_16x16x32_bf16(__builtin_bit_cast(bf16x8,qre[1]),  __builtin_bit_cast(bf16x8,bi1), aI[t],0,0,0);
            aI[t] = __builtin_amdgcn_mfma_f32_16x16x32_bf16(__builtin_bit_cast(bf16x8,qim[0]),  __builtin_bit_cast(bf16x8,br0), aI[t],0,0,0);
            aI[t] = __builtin_amdgcn_mfma_f32_16x16x32_bf16(__builtin_bit_cast(bf16x8,qim[1]),  __builtin_bit_cast(bf16x8,br1), aI[t],0,0,0);
        }

        float p_[4][4];
#pragma unroll
        for (int t = 0; t < 4; ++t)
#pragma unroll
            for (int r = 0; r < 4; ++r) {
                float re = aR[t][r], im = aI[t][r];
                p_[t][r] = fexp2_(fsqrt_(fmaf(re, re, im * im)) * C_EXP);
            }
#pragma unroll
        for (int r = 0; r < 4; ++r)
            lsum[r] += (p_[0][r] + p_[1][r]) + (p_[2][r] + p_[3][r]);

        char* const pb = (char*)Pw + w * 2048;
#pragma unroll
        for (int t = 0; t < 4; ++t)
#pragma unroll
            for (int r = 0; r < 4; ++r) {
                const int prow = lg * 4 + r;
                *(unsigned short*)(pb + ((prow * 128 + (t * 16 + lr) * 2) ^ ((prow & 7) << 4)))
                    = f2b(p_[t][r]);
            }
        asm volatile("s_waitcnt lgkmcnt(0)" ::: "memory");
        __builtin_amdgcn_sched_barrier(0);
        const int psw = (lr & 7) << 4;
        u16x8 pf0 = *(const u16x8*)(pb + ((lr * 128 + lg16     ) ^ psw));
        u16x8 pf1 = *(const u16x8*)(pb + ((lr * 128 + 64 + lg16) ^ psw));

#pragma unroll
        for (int dt = 0; dt < 4; ++dt) {
            const int dr = dt * 16 + lr;
            const int swr = (dr & 7) << 4;
            const char* vrre = vb + dr * 128;
            const char* vrim = vb + (64 + dr) * 128;
            u16x8 vr0 = *(const u16x8*)(vrre + (( lg16     ) ^ swr));
            u16x8 vr1 = *(const u16x8*)(vrre + (( 64 + lg16) ^ swr));
            u16x8 vi0 = *(const u16x8*)(vrim + (( lg16     ) ^ swr));
            u16x8 vi1 = *(const u16x8*)(vrim + (( 64 + lg16) ^ swr));
            Ore[dt] = __builtin_amdgcn_mfma_f32_16x16x32_bf16(__builtin_bit_cast(bf16x8,pf0), __builtin_bit_cast(bf16x8,vr0), Ore[dt],0,0,0);
            Ore[dt] = __builtin_amdgcn_mfma_f32_16x16x32_bf16(__builtin_bit_cast(bf16x8,pf1), __builtin_bit_cast(bf16x8,vr1), Ore[dt],0,0,0);
            Oim[dt] = __builtin_amdgcn_mfma_f32_16x16x32_bf16(__builtin_bit_cast(bf16x8,pf0), __builtin_bit_cast(bf16x8,vi0), Oim[dt],0,0,0);
            Oim[dt] = __builtin_amdgcn_mfma_f32_16x16x32_bf16(__builtin_bit_cast(bf16x8,pf1), __builtin_bit_cast(bf16x8,vi1), Oim[dt],0,0,0);
        }
        __syncthreads();
    }

#pragma unroll
    for (int r = 0; r < 4; ++r) {
        float s = lsum[r];
        s += __shfl_xor(s, 1);
        s += __shfl_xor(s, 2);
        s += __shfl_xor(s, 4);
        s += __shfl_xor(s, 8);
        const float inv = 1.0f / s;
        const int lq = qblk * 64 + w * 16 + lg * 4 + r;
        const int obase = (((b * L_ + lq) * H_ + h) * E_) * 2;
#pragma unroll
        for (int dt = 0; dt < 4; ++dt) {
            const int d = dt * 16 + lr;
            float2 val = make_float2(Ore[dt][r] * inv, Oim[dt][r] * inv);
            *(float2*)(out + obase + d * 2) = val;
        }
    }
}

extern "C" void kernel_launch(void* const* d_in, const int* in_sizes, int n_in,
                              void* d_out, int out_size, void* d_ws, size_t ws_size,
                              hipStream_t stream) {
    const float* q_re = (const float*)d_in[0];
    const float* q_im = (const float*)d_in[1];
    const float* k_re = (const float*)d_in[2];
    const float* k_im = (const float*)d_in[3];
    const float* v_re = (const float*)d_in[4];
    const float* v_im = (const float*)d_in[5];
    float* out = (float*)d_out;

    if (ws_size >= WS_NEEDED) {
        char* ws = (char*)d_ws;
        hipLaunchKernelGGL(ffa_prepack, dim3(B_ * H_ * NT), dim3(256), 0, stream,
                           k_re, k_im, v_re, v_im, ws);
        hipLaunchKernelGGL(ffa_main, dim3(B_ * H_ * (L_ / QB)), dim3(256), 0, stream,
                           q_re, q_im, (const char*)ws, out);
    } else {
        hipLaunchKernelGGL(ffa_fwd_fb, dim3(B_ * H_ * (L_ / 64)), dim3(256), 0, stream,
                           q_re, q_im, k_re, k_im, v_re, v_im, out);
    }
}